// Round 8
// baseline (131.049 us; speedup 1.0000x reference)
//
#include <hip/hip_runtime.h>
#include <stdint.h>

// DBMLLoss on MI355X — round 8: counted-vmcnt pipelined phase kernel.
// feats: [4096,512] f32 (L2-normalized rows), labels: [4096] i32, out: scalar f32.
// Path A: phase1 = GEMM + pass-1 fold + bf16 sim write (simb[c][r], valid by symmetry);
//   pass2 = streaming per-row fold fused with slot-reduce + finalize.
// K-loop schedule (T4): prefetch depth 2, per step
//   {vmcnt(4); s_barrier; 16 MFMA; lgkmcnt(0); s_barrier; stage(s+2)}
// so the barrier waits on loads issued TWO steps (~5000 cy) ago -> no latency on the
// critical path. All frag/staging addresses hoisted to thread-constant bases.

#define Bn 4096
#define Dk 512
#define NCHUNK 16         // col chunks; grid = 32 x 16 = 512 blocks
#define CWIDTH 256        // cols per chunk
#define BM 128            // rows per block
#define TBN 128           // cols per tile step
#define ONE_EPS 0.99999f  // 1 - 1e-5

typedef short bf16x8 __attribute__((ext_vector_type(8)));
typedef unsigned short u16x4 __attribute__((ext_vector_type(4)));
typedef float f32x4 __attribute__((ext_vector_type(4)));

__device__ __forceinline__ unsigned short f2bf(float x) {
  unsigned int u = __float_as_uint(x);
  u += 0x7fffu + ((u >> 16) & 1u);   // RNE
  return (unsigned short)(u >> 16);
}

// featT layout: [kb 0..63][row 0..4095][8 bf16]  (kb = k/8)
__global__ __launch_bounds__(256) void convert_kernel(const float* __restrict__ feats,
                                                      unsigned short* __restrict__ featT) {
  int g = blockIdx.x * 256 + threadIdx.x;  // g = kb*4096 + row
  int row = g & 4095;
  int kb = g >> 12;
  const float* src = feats + (size_t)row * Dk + kb * 8;
  f32x4 f0 = *(const f32x4*)(src);
  f32x4 f1 = *(const f32x4*)(src + 4);
  union { unsigned short u[8]; bf16x8 v; } o;
  o.u[0] = f2bf(f0[0]); o.u[1] = f2bf(f0[1]); o.u[2] = f2bf(f0[2]); o.u[3] = f2bf(f0[3]);
  o.u[4] = f2bf(f1[0]); o.u[5] = f2bf(f1[1]); o.u[6] = f2bf(f1[2]); o.u[7] = f2bf(f1[3]);
  *(bf16x8*)(featT + (size_t)g * 8) = o.v;
}

__device__ __forceinline__ void gload16(const unsigned short* g, short* l) {
  __builtin_amdgcn_global_load_lds((const __attribute__((address_space(1))) unsigned int*)g,
                                   (__attribute__((address_space(3))) unsigned int*)l,
                                   16, 0, 0);
}

// PHASE 1 partials (5): sum, sumsq, max_neg, min_pos, pos_cnt  (+ optional sim write)
// PHASE 2 partials (6): fallback path only
template <int PHASE, bool WSIM>
__global__ __launch_bounds__(512, 2) void phase_kernel(const unsigned short* __restrict__ featT,
                                                       const int* __restrict__ labels,
                                                       const float* __restrict__ rs,
                                                       float* __restrict__ part,
                                                       unsigned short* __restrict__ simb) {
  // double-buffered LDS tiles, k-outer: [kb 0..7][r 0..127][8 bf16]
  __shared__ short As[2][8192];
  __shared__ short Bs[2][8192];
  __shared__ int rl[BM];
  __shared__ int cl[CWIDTH];

  const int tid = threadIdx.x;
  const int wid = tid >> 6;
  const int lane = tid & 63;
  const int WR = wid & 3;    // 4 row groups of 32
  const int WC = wid >> 2;   // 2 col groups of 64
  const int l15 = lane & 15;
  const int l4 = lane >> 4;
  const int row0 = blockIdx.x * BM;
  const int chunk0 = blockIdx.y * CWIDTH;

  // ---- thread-constant staging bases ----
  const unsigned short* aSrc[2]; const unsigned short* bSrc[2];
  short* aDst[2]; short* bDst[2];
#pragma unroll
  for (int i = 0; i < 2; ++i) {
    const int q = tid + i * 512;
    const int r = q & 127;
    const int kb = q >> 7;
    aSrc[i] = featT + ((size_t)kb * Bn + row0 + r) * 8;
    bSrc[i] = featT + ((size_t)kb * Bn + chunk0 + r) * 8;
    aDst[i] = &As[0][0] + q * 8;
    bDst[i] = &Bs[0][0] + q * 8;
  }
  // stage step s: (kt = s&7, ct = s>>3) into buf s&1
  auto stage = [&](int s) {
    const int kt = s & 7, ct = s >> 3, bb = s & 1;
    const size_t ko = (size_t)kt * 262144;  // kt*8*Bn*8 shorts
#pragma unroll
    for (int i = 0; i < 2; ++i) {
      gload16(aSrc[i] + ko, aDst[i] + bb * 8192);
      gload16(bSrc[i] + ko + ct * 1024, bDst[i] + bb * 8192);
    }
  };

  stage(0);
  stage(1);

  if (tid < BM) rl[tid] = labels[row0 + tid];
  if (tid < CWIDTH) cl[tid] = labels[chunk0 + tid];
  asm volatile("s_waitcnt lgkmcnt(0)" ::: "memory");  // label ds_writes done (pre-barrier)

  int rlab[2][4], rowl[2][4];
  float thrp[2][4], thrn[2][4];
#pragma unroll
  for (int m = 0; m < 2; ++m)
#pragma unroll
    for (int r = 0; r < 4; ++r) {
      int lr = WR * 32 + m * 16 + l4 * 4 + r;  // C/D: row=(l>>4)*4+reg
      rowl[m][r] = lr;
      rlab[m][r] = 0;
      if constexpr (PHASE == 2) {
        thrp[m][r] = rs[2 * Bn + row0 + lr];  // max_neg
        thrn[m][r] = rs[3 * Bn + row0 + lr];  // min_pos
      }
    }

  float s0[2][4], s1[2][4], s2[2][4], s3[2][4], s4[2][4], s5[2][4];
#pragma unroll
  for (int m = 0; m < 2; ++m)
#pragma unroll
    for (int r = 0; r < 4; ++r) {
      s0[m][r] = 0.f; s1[m][r] = 0.f;
      s2[m][r] = (PHASE == 1) ? -__builtin_inff() : 0.f;
      s3[m][r] = (PHASE == 1) ? __builtin_inff() : 0.f;
      s4[m][r] = 0.f; s5[m][r] = 0.f;
    }

  f32x4 acc[2][4];
#pragma unroll
  for (int m = 0; m < 2; ++m)
#pragma unroll
    for (int n = 0; n < 4; ++n) acc[m][n] = (f32x4){0.f, 0.f, 0.f, 0.f};

  // fixed per-thread frag offsets (shorts) within a buffer
  const int aFixed = l4 * 1024 + WR * 256 + l15 * 8;
  const int bFixed = l4 * 1024 + WC * 512 + l15 * 8;

  // ---- fold tile ct from acc into stats (+ optional sim write), then caller resets acc
  auto fold = [&](int ct) {
    const int col0 = chunk0 + ct * TBN;
    const bool diag = (col0 == row0);
#pragma unroll
    for (int n = 0; n < 4; ++n) {
      const int lcolt = WC * 64 + n * 16 + l15;
      const int clab = cl[ct * TBN + lcolt];
#pragma unroll
      for (int m = 0; m < 2; ++m) {
        float tv[4];
#pragma unroll
        for (int r = 0; r < 4; ++r) {
          float s = acc[m][n][r];
          if (diag && (lcolt == rowl[m][r])) s = 1.0f;  // exact self-sim
          tv[r] = s;
        }
        if constexpr (WSIM) {
          u16x4 w;
#pragma unroll
          for (int r = 0; r < 4; ++r) w[r] = f2bf(tv[r]);
          // simb[c][r]: by symmetry this is sim row c.
          *(u16x4*)(simb + (size_t)(col0 + lcolt) * Bn +
                    (row0 + WR * 32 + m * 16 + l4 * 4)) = w;
        }
#pragma unroll
        for (int r = 0; r < 4; ++r) {
          float s = tv[r];
          bool same = (rlab[m][r] == clab);
          if constexpr (PHASE == 1) {
            s0[m][r] += s;
            s1[m][r] += s * s;
            if (!same) s2[m][r] = fmaxf(s2[m][r], s);
            else if (s < ONE_EPS) { s3[m][r] = fminf(s3[m][r], s); s4[m][r] += 1.0f; }
          } else {
            bool psel = same && (s < ONE_EPS) && (s - 0.1f < thrp[m][r]);
            bool nsel = (!same) && (s + 0.1f > thrn[m][r]);
            if (psel) { s0[m][r] += 1.0f; s4[m][r] += __expf(2.0f - 2.0f * s); }
            if (nsel) { s1[m][r] += 1.0f; s5[m][r] += __expf(2.0f * s - 1.2f); }
            if (psel || nsel) { s2[m][r] += s; s3[m][r] += s * s; }
          }
        }
      }
    }
  };

  // ---- K-loop: counted-vmcnt, depth-2 prefetch ----
  for (int s = 0; s < 16; ++s) {
    if (s < 15) asm volatile("s_waitcnt vmcnt(4)" ::: "memory");  // stage(s) landed
    else        asm volatile("s_waitcnt vmcnt(0)" ::: "memory");
    __builtin_amdgcn_s_barrier();   // everyone's stage(s) landed
    if (s == 0) {
#pragma unroll
      for (int m = 0; m < 2; ++m)
#pragma unroll
        for (int r = 0; r < 4; ++r) rlab[m][r] = rl[rowl[m][r]];
    }
    const int bb = s & 1;
    const short* Ab = &As[0][0] + bb * 8192 + aFixed;
    const short* Bb = &Bs[0][0] + bb * 8192 + bFixed;
#pragma unroll
    for (int ks = 0; ks < 2; ++ks) {
      bf16x8 af[2], bf[4];
#pragma unroll
      for (int m = 0; m < 2; ++m)
        af[m] = *(const bf16x8*)(Ab + ks * 4096 + m * 128);
#pragma unroll
      for (int n = 0; n < 4; ++n)
        bf[n] = *(const bf16x8*)(Bb + ks * 4096 + n * 128);
#pragma unroll
      for (int m = 0; m < 2; ++m)
#pragma unroll
        for (int n = 0; n < 4; ++n)
          acc[m][n] = __builtin_amdgcn_mfma_f32_16x16x32_bf16(af[m], bf[n], acc[m][n], 0, 0, 0);
    }
    asm volatile("s_waitcnt lgkmcnt(0)" ::: "memory");  // my reads of buf bb done
    __builtin_amdgcn_s_barrier();                       // everyone's reads done (WAR)
    if (s + 2 < 16) stage(s + 2);                       // overwrite buf bb
    if (s == 7) {
      fold(0);                                          // overlaps stage(9)'s flight
#pragma unroll
      for (int m = 0; m < 2; ++m)
#pragma unroll
        for (int n = 0; n < 4; ++n) acc[m][n] = (f32x4){0.f, 0.f, 0.f, 0.f};
    }
  }
  fold(1);

  // ---- butterfly across the 16 lanes holding different cols of the same rows ----
#pragma unroll
  for (int d = 1; d < 16; d <<= 1) {
#pragma unroll
    for (int m = 0; m < 2; ++m)
#pragma unroll
      for (int r = 0; r < 4; ++r) {
        s0[m][r] += __shfl_xor(s0[m][r], d);
        s1[m][r] += __shfl_xor(s1[m][r], d);
        if constexpr (PHASE == 1) {
          s2[m][r] = fmaxf(s2[m][r], __shfl_xor(s2[m][r], d));
          s3[m][r] = fminf(s3[m][r], __shfl_xor(s3[m][r], d));
          s4[m][r] += __shfl_xor(s4[m][r], d);
        } else {
          s2[m][r] += __shfl_xor(s2[m][r], d);
          s3[m][r] += __shfl_xor(s3[m][r], d);
          s4[m][r] += __shfl_xor(s4[m][r], d);
          s5[m][r] += __shfl_xor(s5[m][r], d);
        }
      }
  }

  // ---- merge the two WC halves in LDS, then one write per row per block ----
  __syncthreads();  // all compute done; reuse As as float scratch
  float* mbuf = (float*)&As[0][0];  // BM*6 floats = 3 KB
  if (WC == 1 && l15 == 0) {
#pragma unroll
    for (int m = 0; m < 2; ++m)
#pragma unroll
      for (int r = 0; r < 4; ++r) {
        int lr = rowl[m][r];
        mbuf[lr * 6 + 0] = s0[m][r];
        mbuf[lr * 6 + 1] = s1[m][r];
        mbuf[lr * 6 + 2] = s2[m][r];
        mbuf[lr * 6 + 3] = s3[m][r];
        mbuf[lr * 6 + 4] = s4[m][r];
        mbuf[lr * 6 + 5] = s5[m][r];
      }
  }
  __syncthreads();
  if (WC == 0 && l15 == 0) {
    const int slot = blockIdx.y;  // 16 slots per row
#pragma unroll
    for (int m = 0; m < 2; ++m)
#pragma unroll
      for (int r = 0; r < 4; ++r) {
        int lr = rowl[m][r];
        int rowg = row0 + lr;
        const float* p = &mbuf[lr * 6];
        float t0 = s0[m][r] + p[0];
        float t1 = s1[m][r] + p[1];
        float t2, t3;
        if constexpr (PHASE == 1) {
          t2 = fmaxf(s2[m][r], p[2]);
          t3 = fminf(s3[m][r], p[3]);
        } else {
          t2 = s2[m][r] + p[2];
          t3 = s3[m][r] + p[3];
        }
        float t4 = s4[m][r] + p[4];
        part[(size_t)(0 * Bn + rowg) * 16 + slot] = t0;
        part[(size_t)(1 * Bn + rowg) * 16 + slot] = t1;
        part[(size_t)(2 * Bn + rowg) * 16 + slot] = t2;
        part[(size_t)(3 * Bn + rowg) * 16 + slot] = t3;
        part[(size_t)(4 * Bn + rowg) * 16 + slot] = t4;
        if constexpr (PHASE == 2)
          part[(size_t)(5 * Bn + rowg) * 16 + slot] = s5[m][r] + p[5];
      }
  }
}

// ---- Path A pass 2: one wave per row (4 rows/block); slot-reduce + stream + finalize ----
__global__ __launch_bounds__(256) void pass2_kernel(const unsigned short* __restrict__ simb,
                                                    const int* __restrict__ labels,
                                                    const float* __restrict__ p1,
                                                    float* __restrict__ out) {
  __shared__ int cl[Bn];  // all 4096 labels, 16 KB
  __shared__ float bs[4];
  const int tid = threadIdx.x;
  for (int i = tid; i < Bn / 4; i += 256) ((int4*)cl)[i] = ((const int4*)labels)[i];
  __syncthreads();
  const int lane = tid & 63;
  const int wv = tid >> 6;
  const int row = blockIdx.x * 4 + wv;
  const int rlab = cl[row];

  // pass-1 slot reduce (16 slots, lanes duplicate in 16-groups)
  const int sl = lane & 15;
  float ssum = p1[(size_t)(0 * Bn + row) * 16 + sl];
  float sssq = p1[(size_t)(1 * Bn + row) * 16 + sl];
  float smxn = p1[(size_t)(2 * Bn + row) * 16 + sl];
  float smnp = p1[(size_t)(3 * Bn + row) * 16 + sl];
  float spc  = p1[(size_t)(4 * Bn + row) * 16 + sl];
#pragma unroll
  for (int d = 1; d < 16; d <<= 1) {
    ssum += __shfl_xor(ssum, d);
    sssq += __shfl_xor(sssq, d);
    smxn = fmaxf(smxn, __shfl_xor(smxn, d));
    smnp = fminf(smnp, __shfl_xor(smnp, d));
    spc += __shfl_xor(spc, d);
  }
  const float thrp = smxn;  // max_neg
  const float thrn = smnp;  // min_pos

  float np = 0.f, nn = 0.f, ssel = 0.f, qsel = 0.f, fp = 0.f, fn = 0.f;
  const unsigned short* rp = simb + (size_t)row * Bn;
#pragma unroll
  for (int it = 0; it < 8; ++it) {
    const int base = it * 512 + lane * 8;
    bf16x8 v = *(const bf16x8*)(rp + base);
    int4 la = *(const int4*)&cl[base];
    int4 lb = *(const int4*)&cl[base + 4];
    int lv[8] = {la.x, la.y, la.z, la.w, lb.x, lb.y, lb.z, lb.w};
#pragma unroll
    for (int e = 0; e < 8; ++e) {
      float s = __uint_as_float(((unsigned int)(unsigned short)v[e]) << 16);
      bool same = (lv[e] == rlab);
      bool psel = same && (s < ONE_EPS) && (s - 0.1f < thrp);
      bool nsel = (!same) && (s + 0.1f > thrn);
      if (psel) { np += 1.f; fp += __expf(2.0f - 2.0f * s); }
      if (nsel) { nn += 1.f; fn += __expf(2.0f * s - 1.2f); }
      if (psel || nsel) { ssel += s; qsel += s * s; }
    }
  }
#pragma unroll
  for (int d = 1; d < 64; d <<= 1) {
    np += __shfl_xor(np, d); nn += __shfl_xor(nn, d);
    ssel += __shfl_xor(ssel, d); qsel += __shfl_xor(qsel, d);
    fp += __shfl_xor(fp, d); fn += __shfl_xor(fn, d);
  }

  float mean_all = ssum * (1.0f / Bn);
  float sigma_all = sssq - (float)Bn * mean_all * mean_all;
  float cnt = fmaxf(np + nn, 1.0f);
  float mean_sel = ssel / cnt;
  float sigma_sel = qsel / cnt - mean_sel * mean_sel;
  float loss = __logf(1.0f + fp) + __logf(1.0f + fn) +
               0.5f * (fabsf(mean_all - mean_sel) + fabsf(sigma_all - sigma_sel));
  bool valid = (spc > 0.5f) && (spc < (float)(Bn - 1) - 0.5f) && (np > 0.5f) && (nn > 0.5f);
  float v0 = valid ? loss : 0.f;

  if (lane == 0) bs[wv] = v0;
  __syncthreads();
  if (tid == 0) atomicAdd(out, (bs[0] + bs[1] + bs[2] + bs[3]) * (1.0f / (float)Bn));
}

// ---- Path B (fallback) helpers ----
__global__ __launch_bounds__(256) void reduce1_kernel(const float* __restrict__ part,
                                                      float* __restrict__ rs) {
  int row = blockIdx.x * 256 + threadIdx.x;
  float sum = 0.f, ssq = 0.f, pc = 0.f;
  float mxn = -__builtin_inff(), mnp = __builtin_inff();
#pragma unroll
  for (int sl = 0; sl < 16; ++sl) {
    sum += part[(size_t)(0 * Bn + row) * 16 + sl];
    ssq += part[(size_t)(1 * Bn + row) * 16 + sl];
    mxn = fmaxf(mxn, part[(size_t)(2 * Bn + row) * 16 + sl]);
    mnp = fminf(mnp, part[(size_t)(3 * Bn + row) * 16 + sl]);
    pc += part[(size_t)(4 * Bn + row) * 16 + sl];
  }
  rs[0 * Bn + row] = sum;
  rs[1 * Bn + row] = ssq;
  rs[2 * Bn + row] = mxn;
  rs[3 * Bn + row] = mnp;
  rs[4 * Bn + row] = pc;
}

__global__ __launch_bounds__(256) void finalize_kernel(const float* __restrict__ p2,
                                                       const float* __restrict__ rs,
                                                       float* __restrict__ out) {
  int tid = threadIdx.x;
  int row = blockIdx.x * 256 + tid;
  float np = 0.f, nn = 0.f, ssel = 0.f, qsel = 0.f, fp = 0.f, fn = 0.f;
#pragma unroll
  for (int sl = 0; sl < 16; ++sl) {
    np += p2[(size_t)(0 * Bn + row) * 16 + sl];
    nn += p2[(size_t)(1 * Bn + row) * 16 + sl];
    ssel += p2[(size_t)(2 * Bn + row) * 16 + sl];
    qsel += p2[(size_t)(3 * Bn + row) * 16 + sl];
    fp += p2[(size_t)(4 * Bn + row) * 16 + sl];
    fn += p2[(size_t)(5 * Bn + row) * 16 + sl];
  }
  float sumall = rs[0 * Bn + row];
  float ssqall = rs[1 * Bn + row];
  float pc = rs[4 * Bn + row];

  float mean_all = sumall * (1.0f / Bn);
  float sigma_all = ssqall - (float)Bn * mean_all * mean_all;
  float cnt = fmaxf(np + nn, 1.0f);
  float mean_sel = ssel / cnt;
  float sigma_sel = qsel / cnt - mean_sel * mean_sel;
  float loss = __logf(1.0f + fp) + __logf(1.0f + fn) +
               0.5f * (fabsf(mean_all - mean_sel) + fabsf(sigma_all - sigma_sel));
  bool valid = (pc > 0.5f) && (pc < (float)(Bn - 1) - 0.5f) && (np > 0.5f) && (nn > 0.5f);
  float v = valid ? loss : 0.f;
#pragma unroll
  for (int d = 1; d < 64; d <<= 1) v += __shfl_xor(v, d);
  __shared__ float ls[4];
  if ((tid & 63) == 0) ls[tid >> 6] = v;
  __syncthreads();
  if (tid == 0) atomicAdd(out, (ls[0] + ls[1] + ls[2] + ls[3]) * (1.0f / (float)Bn));
}

extern "C" void kernel_launch(void* const* d_in, const int* in_sizes, int n_in,
                              void* d_out, int out_size, void* d_ws, size_t ws_size,
                              hipStream_t stream) {
  const float* feats = (const float*)d_in[0];
  const int* labels = (const int*)d_in[1];
  float* out = (float*)d_out;
  char* ws = (char*)d_ws;

  unsigned short* featT = (unsigned short*)ws;                      // 4,194,304
  float* p1 = (float*)(ws + 4194304);                               // 5*4096*16*4 = 1,310,720
  const size_t needA = 4194304ull + 1310720ull + 33554432ull;       // + simb 32MB

  hipMemsetAsync(d_out, 0, sizeof(float), stream);
  convert_kernel<<<1024, 256, 0, stream>>>(feats, featT);
  dim3 g(Bn / BM, NCHUNK);

  if (ws_size >= needA) {
    // Path A: single GEMM with sim materialization, then streaming pass 2.
    unsigned short* simb = (unsigned short*)(ws + 4194304 + 1310720);
    phase_kernel<1, true><<<g, 512, 0, stream>>>(featT, labels, nullptr, p1, simb);
    pass2_kernel<<<Bn / 4, 256, 0, stream>>>(simb, labels, p1, out);
  } else {
    // Path B: two-GEMM structure.
    float* rs = (float*)(ws + 4194304 + 1310720);                   // 81,920
    float* p2 = (float*)(ws + 4194304 + 1310720 + 81920);           // 1,572,864
    phase_kernel<1, false><<<g, 512, 0, stream>>>(featT, labels, nullptr, p1, nullptr);
    reduce1_kernel<<<Bn / 256, 256, 0, stream>>>(p1, rs);
    phase_kernel<2, false><<<g, 512, 0, stream>>>(featT, labels, rs, p2, nullptr);
    finalize_kernel<<<Bn / 256, 256, 0, stream>>>(p2, rs, out);
  }
}

// Round 9
// 122.166 us; speedup vs baseline: 1.0727x; 1.0727x over previous
//
#include <hip/hip_runtime.h>
#include <stdint.h>

// DBMLLoss on MI355X — round 9.
// feats: [4096,512] f32 (L2-normalized rows), labels: [4096] i32, out: scalar f32.
// Path A: convert -> phase1 (GEMM + pass-1 fold + bf16 sim write, round-7 verified)
//         -> pass2 (4096 blocks, 1 row/block, plain store per row) -> sum (no atomics).
// Round-8 lesson: counted-vmcnt/raw-barrier K-loop was neutral-to-worse (compiler's
// __syncthreads schedule already fine); reverted. Round-9 target: the ~80us of
// non-phase1 time — pass2's 1024 same-address atomicAdds removed entirely.

#define Bn 4096
#define Dk 512
#define NCHUNK 16         // col chunks; grid = 32 x 16 = 512 blocks
#define CWIDTH 256        // cols per chunk
#define BM 128            // rows per block
#define TBN 128           // cols per tile step
#define BK 64             // K step
#define NSTEP 16          // (CWIDTH/TBN) * (Dk/BK)
#define ONE_EPS 0.99999f  // 1 - 1e-5

typedef short bf16x8 __attribute__((ext_vector_type(8)));
typedef unsigned short u16x4 __attribute__((ext_vector_type(4)));
typedef float f32x4 __attribute__((ext_vector_type(4)));

__device__ __forceinline__ unsigned short f2bf(float x) {
  unsigned int u = __float_as_uint(x);
  u += 0x7fffu + ((u >> 16) & 1u);   // RNE
  return (unsigned short)(u >> 16);
}

// featT layout: [kb 0..63][row 0..4095][8 bf16]  (kb = k/8)
__global__ __launch_bounds__(256) void convert_kernel(const float* __restrict__ feats,
                                                      unsigned short* __restrict__ featT) {
  int g = blockIdx.x * 256 + threadIdx.x;  // g = kb*4096 + row
  int row = g & 4095;
  int kb = g >> 12;
  const float* src = feats + (size_t)row * Dk + kb * 8;
  f32x4 f0 = *(const f32x4*)(src);
  f32x4 f1 = *(const f32x4*)(src + 4);
  union { unsigned short u[8]; bf16x8 v; } o;
  o.u[0] = f2bf(f0[0]); o.u[1] = f2bf(f0[1]); o.u[2] = f2bf(f0[2]); o.u[3] = f2bf(f0[3]);
  o.u[4] = f2bf(f1[0]); o.u[5] = f2bf(f1[1]); o.u[6] = f2bf(f1[2]); o.u[7] = f2bf(f1[3]);
  *(bf16x8*)(featT + (size_t)g * 8) = o.v;
}

__device__ __forceinline__ void gload16(const unsigned short* g, short* l) {
  __builtin_amdgcn_global_load_lds((const __attribute__((address_space(1))) unsigned int*)g,
                                   (__attribute__((address_space(3))) unsigned int*)l,
                                   16, 0, 0);
}

// PHASE 1 partials (5): sum, sumsq, max_neg, min_pos, pos_cnt  (+ optional sim write)
// PHASE 2 partials (6): fallback path only
template <int PHASE, bool WSIM>
__global__ __launch_bounds__(512, 2) void phase_kernel(const unsigned short* __restrict__ featT,
                                                       const int* __restrict__ labels,
                                                       const float* __restrict__ rs,
                                                       float* __restrict__ part,
                                                       unsigned short* __restrict__ simb) {
  // double-buffered LDS tiles, k-outer: [kb 0..7][r 0..127][8 bf16]
  __shared__ short As[2][8192];
  __shared__ short Bs[2][8192];
  __shared__ int rl[BM];
  __shared__ int cl[CWIDTH];

  const int tid = threadIdx.x;
  const int wid = tid >> 6;
  const int lane = tid & 63;
  const int WR = wid & 3;    // 4 row groups of 32
  const int WC = wid >> 2;   // 2 col groups of 64
  const int l15 = lane & 15;
  const int l4 = lane >> 4;
  const int row0 = blockIdx.x * BM;
  const int chunk0 = blockIdx.y * CWIDTH;

  if (tid < BM) rl[tid] = labels[row0 + tid];
  if (tid < CWIDTH) cl[tid] = labels[chunk0 + tid];

  int rlab[2][4], rowl[2][4];
  float thrp[2][4], thrn[2][4];
#pragma unroll
  for (int m = 0; m < 2; ++m)
#pragma unroll
    for (int r = 0; r < 4; ++r) {
      int lr = WR * 32 + m * 16 + l4 * 4 + r;  // tile-local row (C/D: row=(l>>4)*4+reg)
      rowl[m][r] = lr;
      rlab[m][r] = 0;
      if constexpr (PHASE == 2) {
        thrp[m][r] = rs[2 * Bn + row0 + lr];  // max_neg
        thrn[m][r] = rs[3 * Bn + row0 + lr];  // min_pos
      }
    }

  float s0[2][4], s1[2][4], s2[2][4], s3[2][4], s4[2][4], s5[2][4];
#pragma unroll
  for (int m = 0; m < 2; ++m)
#pragma unroll
    for (int r = 0; r < 4; ++r) {
      s0[m][r] = 0.f; s1[m][r] = 0.f;
      s2[m][r] = (PHASE == 1) ? -__builtin_inff() : 0.f;
      s3[m][r] = (PHASE == 1) ? __builtin_inff() : 0.f;
      s4[m][r] = 0.f; s5[m][r] = 0.f;
    }

  // stage step s: A rows panel + B cols panel for (ct = s>>3, kt = s&7) into buf s&1
  auto stage = [&](int s) {
    const int ct = s >> 3, kt = s & 7, bb = s & 1;
    const int cbase = chunk0 + ct * TBN;
#pragma unroll
    for (int i = 0; i < 2; ++i) {
      const int q = tid + i * 512;
      const int r = q & 127;
      const int kb = q >> 7;
      const int ko = (kt * 8 + kb) * (Bn * 8);
      gload16(featT + ko + (row0 + r) * 8, &As[bb][q * 8]);
      gload16(featT + ko + (cbase + r) * 8, &Bs[bb][q * 8]);
    }
  };

  stage(0);

  for (int ct = 0; ct < CWIDTH / TBN; ++ct) {
    const int col0 = chunk0 + ct * TBN;
    f32x4 acc[2][4];
#pragma unroll
    for (int m = 0; m < 2; ++m)
#pragma unroll
      for (int n = 0; n < 4; ++n) acc[m][n] = (f32x4){0.f, 0.f, 0.f, 0.f};

    for (int kt = 0; kt < Dk / BK; ++kt) {
      const int s = ct * 8 + kt;
      __syncthreads();  // drains stage(s) (issued a full compute phase ago) + publishes
      if (s + 1 < NSTEP) stage(s + 1);
      if (s == 0) {  // labels now visible
#pragma unroll
        for (int m = 0; m < 2; ++m)
#pragma unroll
          for (int r = 0; r < 4; ++r) rlab[m][r] = rl[rowl[m][r]];
      }
      const int bb = s & 1;
#pragma unroll
      for (int ks = 0; ks < 2; ++ks) {
        const int kb = ks * 4 + l4;
        bf16x8 af[2], bf[4];
#pragma unroll
        for (int m = 0; m < 2; ++m)
          af[m] = *(const bf16x8*)&As[bb][(kb * 128 + WR * 32 + m * 16 + l15) * 8];
#pragma unroll
        for (int n = 0; n < 4; ++n)
          bf[n] = *(const bf16x8*)&Bs[bb][(kb * 128 + WC * 64 + n * 16 + l15) * 8];
#pragma unroll
        for (int m = 0; m < 2; ++m)
#pragma unroll
          for (int n = 0; n < 4; ++n)
            acc[m][n] = __builtin_amdgcn_mfma_f32_16x16x32_bf16(af[m], bf[n], acc[m][n], 0, 0, 0);
      }
    }

    // ---- fold this 128x128 tile into per-lane row stats (+ optional sim write) ----
    const bool diag = (col0 == row0);
#pragma unroll
    for (int n = 0; n < 4; ++n) {
      const int lcolt = WC * 64 + n * 16 + l15;            // tile-local col
      const int clab = cl[ct * TBN + lcolt];
#pragma unroll
      for (int m = 0; m < 2; ++m) {
        float tv[4];
#pragma unroll
        for (int r = 0; r < 4; ++r) {
          float s = acc[m][n][r];
          if (diag && (lcolt == rowl[m][r])) s = 1.0f;  // exact self-sim
          tv[r] = s;
        }
        if constexpr (WSIM) {
          u16x4 w;
#pragma unroll
          for (int r = 0; r < 4; ++r) w[r] = f2bf(tv[r]);
          // simb[c][r]: by symmetry this is sim row c. 4 consecutive rows -> 8B store.
          *(u16x4*)(simb + (size_t)(col0 + lcolt) * Bn +
                    (row0 + WR * 32 + m * 16 + l4 * 4)) = w;
        }
#pragma unroll
        for (int r = 0; r < 4; ++r) {
          float s = tv[r];
          bool same = (rlab[m][r] == clab);
          if constexpr (PHASE == 1) {
            s0[m][r] += s;
            s1[m][r] += s * s;
            if (!same) s2[m][r] = fmaxf(s2[m][r], s);
            else if (s < ONE_EPS) { s3[m][r] = fminf(s3[m][r], s); s4[m][r] += 1.0f; }
          } else {
            bool psel = same && (s < ONE_EPS) && (s - 0.1f < thrp[m][r]);
            bool nsel = (!same) && (s + 0.1f > thrn[m][r]);
            if (psel) { s0[m][r] += 1.0f; s4[m][r] += __expf(2.0f - 2.0f * s); }
            if (nsel) { s1[m][r] += 1.0f; s5[m][r] += __expf(2.0f * s - 1.2f); }
            if (psel || nsel) { s2[m][r] += s; s3[m][r] += s * s; }
          }
        }
      }
    }
  }

  // butterfly across the 16 lanes holding different cols of the same rows
#pragma unroll
  for (int d = 1; d < 16; d <<= 1) {
#pragma unroll
    for (int m = 0; m < 2; ++m)
#pragma unroll
      for (int r = 0; r < 4; ++r) {
        s0[m][r] += __shfl_xor(s0[m][r], d);
        s1[m][r] += __shfl_xor(s1[m][r], d);
        if constexpr (PHASE == 1) {
          s2[m][r] = fmaxf(s2[m][r], __shfl_xor(s2[m][r], d));
          s3[m][r] = fminf(s3[m][r], __shfl_xor(s3[m][r], d));
          s4[m][r] += __shfl_xor(s4[m][r], d);
        } else {
          s2[m][r] += __shfl_xor(s2[m][r], d);
          s3[m][r] += __shfl_xor(s3[m][r], d);
          s4[m][r] += __shfl_xor(s4[m][r], d);
          s5[m][r] += __shfl_xor(s5[m][r], d);
        }
      }
  }

  // ---- merge the two WC halves in LDS, then one write per row per block ----
  __syncthreads();  // all compute done; reuse As as float scratch
  float* mbuf = (float*)&As[0][0];  // BM*6 floats = 3 KB
  if (WC == 1 && l15 == 0) {
#pragma unroll
    for (int m = 0; m < 2; ++m)
#pragma unroll
      for (int r = 0; r < 4; ++r) {
        int lr = rowl[m][r];
        mbuf[lr * 6 + 0] = s0[m][r];
        mbuf[lr * 6 + 1] = s1[m][r];
        mbuf[lr * 6 + 2] = s2[m][r];
        mbuf[lr * 6 + 3] = s3[m][r];
        mbuf[lr * 6 + 4] = s4[m][r];
        mbuf[lr * 6 + 5] = s5[m][r];
      }
  }
  __syncthreads();
  if (WC == 0 && l15 == 0) {
    const int slot = blockIdx.y;  // 16 slots per row
#pragma unroll
    for (int m = 0; m < 2; ++m)
#pragma unroll
      for (int r = 0; r < 4; ++r) {
        int lr = rowl[m][r];
        int rowg = row0 + lr;
        const float* p = &mbuf[lr * 6];
        float t0 = s0[m][r] + p[0];
        float t1 = s1[m][r] + p[1];
        float t2, t3;
        if constexpr (PHASE == 1) {
          t2 = fmaxf(s2[m][r], p[2]);
          t3 = fminf(s3[m][r], p[3]);
        } else {
          t2 = s2[m][r] + p[2];
          t3 = s3[m][r] + p[3];
        }
        float t4 = s4[m][r] + p[4];
        part[(size_t)(0 * Bn + rowg) * 16 + slot] = t0;
        part[(size_t)(1 * Bn + rowg) * 16 + slot] = t1;
        part[(size_t)(2 * Bn + rowg) * 16 + slot] = t2;
        part[(size_t)(3 * Bn + rowg) * 16 + slot] = t3;
        part[(size_t)(4 * Bn + rowg) * 16 + slot] = t4;
        if constexpr (PHASE == 2)
          part[(size_t)(5 * Bn + rowg) * 16 + slot] = s5[m][r] + p[5];
      }
  }
}

// ---- Path A pass 2: one row per block (4 waves split the row); plain store, no atomics
__global__ __launch_bounds__(256) void pass2_kernel(const unsigned short* __restrict__ simb,
                                                    const int* __restrict__ labels,
                                                    const float* __restrict__ p1,
                                                    float* __restrict__ bres) {
  __shared__ float red[4][6];
  const int tid = threadIdx.x;
  const int lane = tid & 63;
  const int wv = tid >> 6;        // 0..3
  const int row = blockIdx.x;
  const int rlab = labels[row];   // block-uniform -> scalar load

  // pass-1 slot reduce (16 slots; every wave does it redundantly)
  const int sl = lane & 15;
  float ssum = p1[(size_t)(0 * Bn + row) * 16 + sl];
  float sssq = p1[(size_t)(1 * Bn + row) * 16 + sl];
  float smxn = p1[(size_t)(2 * Bn + row) * 16 + sl];
  float smnp = p1[(size_t)(3 * Bn + row) * 16 + sl];
  float spc  = p1[(size_t)(4 * Bn + row) * 16 + sl];
#pragma unroll
  for (int d = 1; d < 16; d <<= 1) {
    ssum += __shfl_xor(ssum, d);
    sssq += __shfl_xor(sssq, d);
    smxn = fmaxf(smxn, __shfl_xor(smxn, d));
    smnp = fminf(smnp, __shfl_xor(smnp, d));
    spc += __shfl_xor(spc, d);
  }
  const float thrp = smxn;  // max_neg
  const float thrn = smnp;  // min_pos

  float np = 0.f, nn = 0.f, ssel = 0.f, qsel = 0.f, fp = 0.f, fn = 0.f;
  const unsigned short* rp = simb + (size_t)row * Bn;
#pragma unroll
  for (int it = 0; it < 2; ++it) {
    const int base = wv * 1024 + it * 512 + lane * 8;
    bf16x8 v = *(const bf16x8*)(rp + base);
    int4 la = *(const int4*)&labels[base];
    int4 lb = *(const int4*)&labels[base + 4];
    int lv[8] = {la.x, la.y, la.z, la.w, lb.x, lb.y, lb.z, lb.w};
#pragma unroll
    for (int e = 0; e < 8; ++e) {
      float s = __uint_as_float(((unsigned int)(unsigned short)v[e]) << 16);
      bool same = (lv[e] == rlab);
      bool psel = same && (s < ONE_EPS) && (s - 0.1f < thrp);
      bool nsel = (!same) && (s + 0.1f > thrn);
      if (psel) { np += 1.f; fp += __expf(2.0f - 2.0f * s); }
      if (nsel) { nn += 1.f; fn += __expf(2.0f * s - 1.2f); }
      if (psel || nsel) { ssel += s; qsel += s * s; }
    }
  }
#pragma unroll
  for (int d = 1; d < 64; d <<= 1) {
    np += __shfl_xor(np, d); nn += __shfl_xor(nn, d);
    ssel += __shfl_xor(ssel, d); qsel += __shfl_xor(qsel, d);
    fp += __shfl_xor(fp, d); fn += __shfl_xor(fn, d);
  }
  if (lane == 0) {
    red[wv][0] = np; red[wv][1] = nn; red[wv][2] = ssel;
    red[wv][3] = qsel; red[wv][4] = fp; red[wv][5] = fn;
  }
  __syncthreads();
  if (tid == 0) {
    np = red[0][0] + red[1][0] + red[2][0] + red[3][0];
    nn = red[0][1] + red[1][1] + red[2][1] + red[3][1];
    ssel = red[0][2] + red[1][2] + red[2][2] + red[3][2];
    qsel = red[0][3] + red[1][3] + red[2][3] + red[3][3];
    fp = red[0][4] + red[1][4] + red[2][4] + red[3][4];
    fn = red[0][5] + red[1][5] + red[2][5] + red[3][5];

    float mean_all = ssum * (1.0f / Bn);
    float sigma_all = sssq - (float)Bn * mean_all * mean_all;
    float cnt = fmaxf(np + nn, 1.0f);
    float mean_sel = ssel / cnt;
    float sigma_sel = qsel / cnt - mean_sel * mean_sel;
    float loss = __logf(1.0f + fp) + __logf(1.0f + fn) +
                 0.5f * (fabsf(mean_all - mean_sel) + fabsf(sigma_all - sigma_sel));
    bool valid = (spc > 0.5f) && (spc < (float)(Bn - 1) - 0.5f) && (np > 0.5f) && (nn > 0.5f);
    bres[row] = valid ? loss : 0.f;
  }
}

// ---- Path A final: sum 4096 per-row losses -> out (single block, no atomics) ----
__global__ __launch_bounds__(256) void sum_kernel(const float* __restrict__ bres,
                                                  float* __restrict__ out) {
  const int tid = threadIdx.x;
  float v = 0.f;
#pragma unroll
  for (int i = 0; i < 16; ++i) v += bres[i * 256 + tid];
#pragma unroll
  for (int d = 1; d < 64; d <<= 1) v += __shfl_xor(v, d);
  __shared__ float ls[4];
  if ((tid & 63) == 0) ls[tid >> 6] = v;
  __syncthreads();
  if (tid == 0) out[0] = (ls[0] + ls[1] + ls[2] + ls[3]) * (1.0f / (float)Bn);
}

// ---- Path B (fallback) helpers ----
__global__ __launch_bounds__(256) void reduce1_kernel(const float* __restrict__ part,
                                                      float* __restrict__ rs) {
  int row = blockIdx.x * 256 + threadIdx.x;
  float sum = 0.f, ssq = 0.f, pc = 0.f;
  float mxn = -__builtin_inff(), mnp = __builtin_inff();
#pragma unroll
  for (int sl = 0; sl < 16; ++sl) {
    sum += part[(size_t)(0 * Bn + row) * 16 + sl];
    ssq += part[(size_t)(1 * Bn + row) * 16 + sl];
    mxn = fmaxf(mxn, part[(size_t)(2 * Bn + row) * 16 + sl]);
    mnp = fminf(mnp, part[(size_t)(3 * Bn + row) * 16 + sl]);
    pc += part[(size_t)(4 * Bn + row) * 16 + sl];
  }
  rs[0 * Bn + row] = sum;
  rs[1 * Bn + row] = ssq;
  rs[2 * Bn + row] = mxn;
  rs[3 * Bn + row] = mnp;
  rs[4 * Bn + row] = pc;
}

__global__ __launch_bounds__(256) void finalize_kernel(const float* __restrict__ p2,
                                                       const float* __restrict__ rs,
                                                       float* __restrict__ out) {
  int tid = threadIdx.x;
  int row = blockIdx.x * 256 + tid;
  float np = 0.f, nn = 0.f, ssel = 0.f, qsel = 0.f, fp = 0.f, fn = 0.f;
#pragma unroll
  for (int sl = 0; sl < 16; ++sl) {
    np += p2[(size_t)(0 * Bn + row) * 16 + sl];
    nn += p2[(size_t)(1 * Bn + row) * 16 + sl];
    ssel += p2[(size_t)(2 * Bn + row) * 16 + sl];
    qsel += p2[(size_t)(3 * Bn + row) * 16 + sl];
    fp += p2[(size_t)(4 * Bn + row) * 16 + sl];
    fn += p2[(size_t)(5 * Bn + row) * 16 + sl];
  }
  float sumall = rs[0 * Bn + row];
  float ssqall = rs[1 * Bn + row];
  float pc = rs[4 * Bn + row];

  float mean_all = sumall * (1.0f / Bn);
  float sigma_all = ssqall - (float)Bn * mean_all * mean_all;
  float cnt = fmaxf(np + nn, 1.0f);
  float mean_sel = ssel / cnt;
  float sigma_sel = qsel / cnt - mean_sel * mean_sel;
  float loss = __logf(1.0f + fp) + __logf(1.0f + fn) +
               0.5f * (fabsf(mean_all - mean_sel) + fabsf(sigma_all - sigma_sel));
  bool valid = (pc > 0.5f) && (pc < (float)(Bn - 1) - 0.5f) && (np > 0.5f) && (nn > 0.5f);
  float v = valid ? loss : 0.f;
#pragma unroll
  for (int d = 1; d < 64; d <<= 1) v += __shfl_xor(v, d);
  __shared__ float ls[4];
  if ((tid & 63) == 0) ls[tid >> 6] = v;
  __syncthreads();
  if (tid == 0) atomicAdd(out, (ls[0] + ls[1] + ls[2] + ls[3]) * (1.0f / (float)Bn));
}

extern "C" void kernel_launch(void* const* d_in, const int* in_sizes, int n_in,
                              void* d_out, int out_size, void* d_ws, size_t ws_size,
                              hipStream_t stream) {
  const float* feats = (const float*)d_in[0];
  const int* labels = (const int*)d_in[1];
  float* out = (float*)d_out;
  char* ws = (char*)d_ws;

  unsigned short* featT = (unsigned short*)ws;                      // 4,194,304
  float* p1 = (float*)(ws + 4194304);                               // 5*4096*16*4 = 1,310,720
  const size_t needA = 4194304ull + 1310720ull + 33554432ull + 16384ull;  // + simb + bres

  convert_kernel<<<1024, 256, 0, stream>>>(feats, featT);
  dim3 g(Bn / BM, NCHUNK);

  if (ws_size >= needA) {
    // Path A: single GEMM with sim materialization, streaming pass 2, no atomics.
    unsigned short* simb = (unsigned short*)(ws + 4194304 + 1310720);
    float* bres = (float*)(ws + 4194304 + 1310720 + 33554432);
    phase_kernel<1, true><<<g, 512, 0, stream>>>(featT, labels, nullptr, p1, simb);
    pass2_kernel<<<Bn, 256, 0, stream>>>(simb, labels, p1, bres);
    sum_kernel<<<1, 256, 0, stream>>>(bres, out);
  } else {
    // Path B: two-GEMM structure.
    float* rs = (float*)(ws + 4194304 + 1310720);                   // 81,920
    float* p2 = (float*)(ws + 4194304 + 1310720 + 81920);           // 1,572,864
    hipMemsetAsync(d_out, 0, sizeof(float), stream);
    phase_kernel<1, false><<<g, 512, 0, stream>>>(featT, labels, nullptr, p1, nullptr);
    reduce1_kernel<<<Bn / 256, 256, 0, stream>>>(p1, rs);
    phase_kernel<2, false><<<g, 512, 0, stream>>>(featT, labels, rs, p2, nullptr);
    finalize_kernel<<<Bn / 256, 256, 0, stream>>>(p2, rs, out);
  }
}